// Round 4
// baseline (232.773 us; speedup 1.0000x reference)
//
#include <hip/hip_runtime.h>

// Problem constants: B=2, S=2048, D_MODEL=1024, H=16, DK=64.
// Workspace need: ~20.5 MB (og aliases st16; see kernel_launch).

#define LOG2E 1.44269504088896f

using f16   = _Float16;
using f16x4 = __attribute__((ext_vector_type(4))) _Float16;
using f16x8 = __attribute__((ext_vector_type(8))) _Float16;
using f32x4 = __attribute__((ext_vector_type(4))) float;

#define GLDS16(g, l) __builtin_amdgcn_global_load_lds((const __attribute__((address_space(1))) void*)(g), (__attribute__((address_space(3))) void*)(l), 16, 0, 0)
#define GLDS4(g, l)  __builtin_amdgcn_global_load_lds((const __attribute__((address_space(1))) void*)(g), (__attribute__((address_space(3))) void*)(l), 4, 0, 0)

// ---------------------------------------------------------------------------
// K1: blocks 0-1023:   s[b,h,k] = states·Wa  (wave per row) + states->fp16
//     blocks 1024-2047: gsig[b,q,h] = sigmoid(states·Wg + bg)
//     blocks 2048-3071: Wv/Wo -> fp16; cb<512: mask absmax partials
// ---------------------------------------------------------------------------
__global__ __launch_bounds__(256) void k_prep(
    const float* __restrict__ states, const float* __restrict__ mask,
    const float* __restrict__ Wa, const float* __restrict__ Wv,
    const float* __restrict__ Wg, const float* __restrict__ Wo,
    const float* __restrict__ bg,
    f16* __restrict__ st16, f16* __restrict__ Wv16, f16* __restrict__ Wo16,
    float* __restrict__ sbuf, float* __restrict__ gsig, float* __restrict__ partial)
{
  __shared__ float ws[16 * 1024];   // 64 KB
  const int bid = blockIdx.x;
  const int t   = threadIdx.x;
  if (bid < 2048) {
    const bool is_g = bid >= 1024;
    const float* W = is_g ? Wg : Wa;
    for (int i = t; i < 4096; i += 256)
      ((float4*)ws)[i] = ((const float4*)W)[i];
    __syncthreads();
    const int wid = t >> 6, lane = t & 63;
    const int row = (bid & 1023) * 4 + wid;           // 0..4095
    const float* sp = states + (size_t)row * 1024 + lane * 16;
    float x[16];
    #pragma unroll
    for (int j = 0; j < 4; ++j) {
      float4 v = ((const float4*)sp)[j];
      x[j*4+0]=v.x; x[j*4+1]=v.y; x[j*4+2]=v.z; x[j*4+3]=v.w;
    }
    if (!is_g) {
      f16x8 h0, h1;
      #pragma unroll
      for (int j = 0; j < 8; ++j) { h0[j] = (f16)x[j]; h1[j] = (f16)x[8+j]; }
      f16* dp = st16 + (size_t)row * 1024 + lane * 16;
      *(f16x8*)dp = h0; *(f16x8*)(dp + 8) = h1;
    }
    const int b = row >> 11, q = row & 2047;
    for (int h = 0; h < 16; ++h) {
      const float4* wr4 = (const float4*)(ws + h * 1024 + lane * 16);
      float acc = 0.f;
      #pragma unroll
      for (int j = 0; j < 4; ++j) {
        float4 wv4 = wr4[j];
        acc = fmaf(x[j*4+0], wv4.x, acc);
        acc = fmaf(x[j*4+1], wv4.y, acc);
        acc = fmaf(x[j*4+2], wv4.z, acc);
        acc = fmaf(x[j*4+3], wv4.w, acc);
      }
      #pragma unroll
      for (int off = 32; off; off >>= 1) acc += __shfl_xor(acc, off, 64);
      if (lane == 0) {
        if (!is_g) sbuf[(size_t)(b * 16 + h) * 2048 + q] = acc;
        else       gsig[(size_t)row * 16 + h] = 1.f / (1.f + __expf(-(acc + bg[h])));
      }
    }
  } else {
    const int cb = bid - 2048;                         // 0..1023
    { // weight convert: 2 M halves total, 2048 per block
      int idx = cb * 2048 + t * 8;
      const float* src; f16* dst;
      if (idx < 1048576) { src = Wv + idx;             dst = Wv16 + idx; }
      else               { src = Wo + (idx - 1048576); dst = Wo16 + (idx - 1048576); }
      float4 v0 = ((const float4*)src)[0];
      float4 v1 = ((const float4*)src)[1];
      f16x8 h;
      h[0]=(f16)v0.x; h[1]=(f16)v0.y; h[2]=(f16)v0.z; h[3]=(f16)v0.w;
      h[4]=(f16)v1.x; h[5]=(f16)v1.y; h[6]=(f16)v1.z; h[7]=(f16)v1.w;
      *(f16x8*)dst = h;
    }
    if (cb < 512) {
      // mask absmax partial: 512 chunks x 16384 floats = 8,388,608 = B*S*S
      const float4* mp = (const float4*)(mask + (size_t)cb * 16384);
      float mx = 0.f;
      for (int i = 0; i < 16; ++i) {
        float4 v = mp[t + i * 256];
        mx = fmaxf(mx, fmaxf(fmaxf(fabsf(v.x), fabsf(v.y)), fmaxf(fabsf(v.z), fabsf(v.w))));
      }
      #pragma unroll
      for (int off = 32; off; off >>= 1) mx = fmaxf(mx, __shfl_xor(mx, off, 64));
      if ((t & 63) == 0) ws[t >> 6] = mx;
      __syncthreads();
      if (t == 0) partial[cb] = fmaxf(fmaxf(ws[0], ws[1]), fmaxf(ws[2], ws[3]));
    }
  }
}

// ---------------------------------------------------------------------------
// K2: L[b,h] = max_k s[b,h,k] + head_scale[h] * max|mask_b|
// ---------------------------------------------------------------------------
__global__ __launch_bounds__(64) void k_lmax(
    const float* __restrict__ sbuf, const float* __restrict__ partial,
    const float* __restrict__ hs, float* __restrict__ Lbuf)
{
  const int bh = blockIdx.x, l = threadIdx.x;
  float mx = -1e30f;
  for (int i = l; i < 2048; i += 64) mx = fmaxf(mx, sbuf[(size_t)bh * 2048 + i]);
  float mm = 0.f;
  const int b = bh >> 4;
  for (int i = l; i < 256; i += 64) mm = fmaxf(mm, partial[b * 256 + i]);
  #pragma unroll
  for (int off = 32; off; off >>= 1) {
    mx = fmaxf(mx, __shfl_xor(mx, off, 64));
    mm = fmaxf(mm, __shfl_xor(mm, off, 64));
  }
  if (l == 0) Lbuf[bh] = mx + hs[bh & 15] * mm;
}

// ---------------------------------------------------------------------------
// K3: vt[(b*1024 + n)][k] = fp16( states[b,k,:]·Wv[n,:] + bv[n] ), V^T layout.
// 128x128 tile, BK=32, double-buffered global_load_lds + counted vmcnt.
// ---------------------------------------------------------------------------
__global__ __launch_bounds__(256) void k_gemm_v(
    const f16* __restrict__ A, const f16* __restrict__ Bw,
    const float* __restrict__ bv, f16* __restrict__ vt)
{
  __shared__ f16 As[8192], Bs[8192];   // 2 buffers each
  const int t = threadIdx.x, wid = t >> 6, lane = t & 63;
  const int r0 = blockIdx.y * 128, n0 = blockIdx.x * 128;
  const int wr = wid >> 1, wc = wid & 1;
  f32x4 acc[4][4] = {};
  const int srow  = t >> 2;
  const int sunit = (t & 3) ^ ((srow >> 1) & 3);
  const f16* ga0 = A  + (size_t)(r0 + srow) * 1024      + sunit * 8;
  const f16* ga1 = A  + (size_t)(r0 + 64 + srow) * 1024 + sunit * 8;
  const f16* gb0 = Bw + (size_t)(n0 + srow) * 1024      + sunit * 8;
  const f16* gb1 = Bw + (size_t)(n0 + 64 + srow) * 1024 + sunit * 8;
  int ra[4], rb[4];
  #pragma unroll
  for (int m = 0; m < 4; ++m) {
    int rr = wr * 64 + m * 16 + (lane & 15);
    ra[m] = rr * 32 + (((lane >> 4) ^ ((rr >> 1) & 3)) * 8);
    rr = wc * 64 + m * 16 + (lane & 15);
    rb[m] = rr * 32 + (((lane >> 4) ^ ((rr >> 1) & 3)) * 8);
  }
  const int ldst = wid * 512;
  #define STAGE_G(kt, bb) do { const int k0_ = (kt) * 32; \
      GLDS16(ga0 + k0_, As + (bb)*4096 + ldst); \
      GLDS16(ga1 + k0_, As + (bb)*4096 + 2048 + ldst); \
      GLDS16(gb0 + k0_, Bs + (bb)*4096 + ldst); \
      GLDS16(gb1 + k0_, Bs + (bb)*4096 + 2048 + ldst); } while(0)
  STAGE_G(0, 0);
  for (int kt = 0; kt < 32; ++kt) {
    const int cur = kt & 1;
    if (kt < 31) {
      STAGE_G(kt + 1, cur ^ 1);
      asm volatile("s_waitcnt vmcnt(4)" ::: "memory");
    } else {
      asm volatile("s_waitcnt vmcnt(0)" ::: "memory");
    }
    asm volatile("s_barrier" ::: "memory");
    f16x8 a[4], b[4];
    #pragma unroll
    for (int m = 0; m < 4; ++m) a[m] = *(const f16x8*)(As + cur*4096 + ra[m]);
    #pragma unroll
    for (int n = 0; n < 4; ++n) b[n] = *(const f16x8*)(Bs + cur*4096 + rb[n]);
    #pragma unroll
    for (int m = 0; m < 4; ++m)
      #pragma unroll
      for (int n = 0; n < 4; ++n)
        acc[m][n] = __builtin_amdgcn_mfma_f32_16x16x32_f16(a[m], b[n], acc[m][n], 0, 0, 0);
    asm volatile("s_waitcnt lgkmcnt(0)" ::: "memory");
    asm volatile("s_barrier" ::: "memory");
  }
  #undef STAGE_G
  const int b_ = r0 >> 11;
  #pragma unroll
  for (int n = 0; n < 4; ++n) {
    const int gn = n0 + wc * 64 + n * 16 + (lane & 15);
    const float bvv = bv[gn];
    #pragma unroll
    for (int m = 0; m < 4; ++m) {
      const int kb = (r0 & 2047) + wr * 64 + m * 16 + ((lane >> 4) << 2);
      f16x4 hv;
      #pragma unroll
      for (int r = 0; r < 4; ++r) hv[r] = (f16)(acc[m][n][r] + bvv);
      *(f16x4*)(vt + (size_t)(b_ * 1024 + gn) * 2048 + kb) = hv;
    }
  }
}

// ---------------------------------------------------------------------------
// K4: fused attention v3. Block = (h, qt=64, b), 256 thr / 4 waves, KVBLK=128.
// k-SPLIT across waves: wave w owns k-chunk w*32 (one K32 MFMA step per m) so
// each V element is ds_read exactly once (no cross-wave V amplification).
// Only V is in LDS (2x16KB dbuf, XOR-swizzled src). mask & s go global->reg
// in A-fragment layout, issued at iter top, consumed after vmcnt+barrier.
// Softmax in-register (no P round-trip, no online rescale: L is precomputed
// logit upper bound). Epilogue: cross-wave acc/den reduce via 16KB LDS alias.
// Grid 1024, bijective chunked XCD swizzle: each XCD = 8 qt x 16 h of one b
// -> mask tile L2-reused across all heads.
// ---------------------------------------------------------------------------
__global__ __launch_bounds__(256, 3) void k_attn(
    const float* __restrict__ mask, const float* __restrict__ sbuf,
    const float* __restrict__ gsig, const float* __restrict__ hs,
    const float* __restrict__ Lbuf, const f16* __restrict__ vt,
    f16* __restrict__ og)
{
  __shared__ __align__(16) f16 vsw[2 * 8192];   // 32 KB V dbuf [64d][16 slots x 8h] swz
  __shared__ float den_l[256];                  // [4 w][64 q]

  const int p = blockIdx.x;                     // 0..1023
  const int l = (p & 7) * 128 + (p >> 3);       // chunked XCD swizzle (bijective)
  const int b = l >> 9, r = l & 511;
  const int qt = r >> 4, h = r & 15;

  const int t = threadIdx.x, wid = t >> 6, lane = t & 63;
  const int lane15 = lane & 15, lg = lane >> 4;
  const float L   = Lbuf[b * 16 + h];
  const float c2  = hs[h] * LOG2E;
  const float nLc = -L * LOG2E;

  const float* mbase = mask + (size_t)b * 4194304;
  const f16*   vtb   = vt + (size_t)(b * 1024 + h * 64) * 2048;

  // mask pointers: q = qt*64 + m*16 + lane15, k = wid*32 + lg*8 (+kv)
  const float* mq0 = mbase + (size_t)(qt * 64 +  0 + lane15) * 2048 + wid * 32 + lg * 8;
  const float* mq1 = mbase + (size_t)(qt * 64 + 16 + lane15) * 2048 + wid * 32 + lg * 8;
  const float* mq2 = mbase + (size_t)(qt * 64 + 32 + lane15) * 2048 + wid * 32 + lg * 8;
  const float* mq3 = mbase + (size_t)(qt * 64 + 48 + lane15) * 2048 + wid * 32 + lg * 8;
  const float* ssrc = sbuf + (size_t)(b * 16 + h) * 2048 + wid * 32 + lg * 8;

  // V staging source (pre-swizzled): d = i*16 + (t>>4), slot' = (t&15)^(t>>4)
  const f16* vsrc = vtb + (size_t)(t >> 4) * 2048 + ((t & 15) ^ (t >> 4)) * 8;
  // V read offset: d = n*16+lane15, slot_r = (wid*4+lg) ^ lane15
  const int voff0 = lane15 * 128 + (((wid << 2) + lg) ^ lane15) * 8;

  f32x4 acc[4][4] = {};
  float den[4] = {0.f, 0.f, 0.f, 0.f};

  // prologue: stage tile 0 into buf 0
  GLDS16(vsrc,         vsw + t * 8);
  GLDS16(vsrc + 32768, vsw + 2048 + t * 8);
  GLDS16(vsrc + 65536, vsw + 4096 + t * 8);
  GLDS16(vsrc + 98304, vsw + 6144 + t * 8);

  #define EXP_MFMA(M, MA, MB) do { \
    f16x8 af_; float dl_; \
    { float w0 = __builtin_amdgcn_exp2f(fmaf(c2, MA[0], sx[0])); \
      float w1 = __builtin_amdgcn_exp2f(fmaf(c2, MA[1], sx[1])); \
      float w2 = __builtin_amdgcn_exp2f(fmaf(c2, MA[2], sx[2])); \
      float w3 = __builtin_amdgcn_exp2f(fmaf(c2, MA[3], sx[3])); \
      float w4 = __builtin_amdgcn_exp2f(fmaf(c2, MB[0], sx[4])); \
      float w5 = __builtin_amdgcn_exp2f(fmaf(c2, MB[1], sx[5])); \
      float w6 = __builtin_amdgcn_exp2f(fmaf(c2, MB[2], sx[6])); \
      float w7 = __builtin_amdgcn_exp2f(fmaf(c2, MB[3], sx[7])); \
      af_[0]=(f16)w0; af_[1]=(f16)w1; af_[2]=(f16)w2; af_[3]=(f16)w3; \
      af_[4]=(f16)w4; af_[5]=(f16)w5; af_[6]=(f16)w6; af_[7]=(f16)w7; \
      dl_ = ((w0+w1)+(w2+w3)) + ((w4+w5)+(w6+w7)); } \
    den[M] += dl_; \
    acc[M][0] = __builtin_amdgcn_mfma_f32_16x16x32_f16(af_, vf0, acc[M][0], 0, 0, 0); \
    acc[M][1] = __builtin_amdgcn_mfma_f32_16x16x32_f16(af_, vf1, acc[M][1], 0, 0, 0); \
    acc[M][2] = __builtin_amdgcn_mfma_f32_16x16x32_f16(af_, vf2, acc[M][2], 0, 0, 0); \
    acc[M][3] = __builtin_amdgcn_mfma_f32_16x16x32_f16(af_, vf3, acc[M][3], 0, 0, 0); \
  } while (0)

  #define ATTN_ITER(KT, CUR, STG) do { \
    const int kv_ = (KT) * 128; \
    f32x4 ma0 = *(const f32x4*)(mq0 + kv_), mb0 = *(const f32x4*)(mq0 + kv_ + 4); \
    f32x4 ma1 = *(const f32x4*)(mq1 + kv_), mb1 = *(const f32x4*)(mq1 + kv_ + 4); \
    f32x4 ma2 = *(const f32x4*)(mq2 + kv_), mb2 = *(const f32x4*)(mq2 + kv_ + 4); \
    f32x4 ma3 = *(const f32x4*)(mq3 + kv_), mb3 = *(const f32x4*)(mq3 + kv_ + 4); \
    f32x4 s0_ = *(const f32x4*)(ssrc + kv_), s1_ = *(const f32x4*)(ssrc + kv_ + 4); \
    if (STG) { \
      const int kn_ = kv_ + 128; \
      GLDS16(vsrc + kn_,         vsw + ((CUR)^1) * 8192 + t * 8); \
      GLDS16(vsrc + 32768 + kn_, vsw + ((CUR)^1) * 8192 + 2048 + t * 8); \
      GLDS16(vsrc + 65536 + kn_, vsw + ((CUR)^1) * 8192 + 4096 + t * 8); \
      GLDS16(vsrc + 98304 + kn_, vsw + ((CUR)^1) * 8192 + 6144 + t * 8); \
      asm volatile("s_waitcnt vmcnt(4)" ::: "memory"); \
    } else { \
      asm volatile("s_waitcnt vmcnt(0)" ::: "memory"); \
    } \
    __builtin_amdgcn_s_barrier(); \
    float sx[8]; \
    sx[0] = fmaf(s0_[0], LOG2E, nLc); sx[1] = fmaf(s0_[1], LOG2E, nLc); \
    sx[2] = fmaf(s0_[2], LOG2E, nLc); sx[3] = fmaf(s0_[3], LOG2E, nLc); \
    sx[4] = fmaf(s1_[0], LOG2E, nLc); sx[5] = fmaf(s1_[1], LOG2E, nLc); \
    sx[6] = fmaf(s1_[2], LOG2E, nLc); sx[7] = fmaf(s1_[3], LOG2E, nLc); \
    const f16* vb_ = vsw + (CUR) * 8192 + voff0; \
    f16x8 vf0 = *(const f16x8*)(vb_); \
    f16x8 vf1 = *(const f16x8*)(vb_ + 2048); \
    f16x8 vf2 = *(const f16x8*)(vb_ + 4096); \
    f16x8 vf3 = *(const f16x8*)(vb_ + 6144); \
    EXP_MFMA(0, ma0, mb0); \
    EXP_MFMA(1, ma1, mb1); \
    EXP_MFMA(2, ma2, mb2); \
    EXP_MFMA(3, ma3, mb3); \
    asm volatile("s_waitcnt lgkmcnt(0)" ::: "memory"); \
    __builtin_amdgcn_s_barrier(); \
  } while (0)

  for (int kt2 = 0; kt2 < 7; ++kt2) {
    ATTN_ITER(kt2 * 2,     0, 1);
    ATTN_ITER(kt2 * 2 + 1, 1, 1);
  }
  ATTN_ITER(14, 0, 1);
  ATTN_ITER(15, 1, 0);
  #undef ATTN_ITER
  #undef EXP_MFMA

  // --- epilogue: den reduce over lg within wave, then cross-wave via LDS ---
  #pragma unroll
  for (int m = 0; m < 4; ++m) {
    den[m] += __shfl_xor(den[m], 16, 64);
    den[m] += __shfl_xor(den[m], 32, 64);
  }
  if (lane < 16) {
    #pragma unroll
    for (int m = 0; m < 4; ++m) den_l[wid * 64 + m * 16 + lane] = den[m];
  }
  __syncthreads();

  float* red = (float*)vsw;                      // 16 KB alias: [4 w][16 q][64 d]
  const int q16 = t >> 4, dch = (t & 15) * 4;
  #pragma unroll
  for (int m = 0; m < 4; ++m) {
    #pragma unroll
    for (int n = 0; n < 4; ++n)
      #pragma unroll
      for (int rr = 0; rr < 4; ++rr)
        red[wid * 1024 + (lg * 4 + rr) * 64 + n * 16 + lane15] = acc[m][n][rr];
    __syncthreads();
    f32x4 o0 = *(const f32x4*)(red +        q16 * 64 + dch);
    f32x4 o1 = *(const f32x4*)(red + 1024 + q16 * 64 + dch);
    f32x4 o2 = *(const f32x4*)(red + 2048 + q16 * 64 + dch);
    f32x4 o3 = *(const f32x4*)(red + 3072 + q16 * 64 + dch);
    f32x4 o = (o0 + o1) + (o2 + o3);
    const float dent = den_l[m * 16 + q16] + den_l[64 + m * 16 + q16] +
                       den_l[128 + m * 16 + q16] + den_l[192 + m * 16 + q16];
    const int q = qt * 64 + m * 16 + q16;
    const float sc = gsig[(size_t)(b * 2048 + q) * 16 + h] / dent;
    f16x4 hv;
    #pragma unroll
    for (int j = 0; j < 4; ++j) hv[j] = (f16)(o[j] * sc);
    *(f16x4*)(og + (size_t)(b * 2048 + q) * 1024 + h * 64 + dch) = hv;
    __syncthreads();
  }
}

// ---------------------------------------------------------------------------
// K5: out[r][n] = og[r,:]·Wo[n,:] + bo[n]  (f32 output), dbuf + counted vmcnt
// ---------------------------------------------------------------------------
__global__ __launch_bounds__(256) void k_gemm_out(
    const f16* __restrict__ A, const f16* __restrict__ Bw,
    const float* __restrict__ bo, float* __restrict__ out)
{
  __shared__ f16 As[8192], Bs[8192];
  const int t = threadIdx.x, wid = t >> 6, lane = t & 63;
  const int r0 = blockIdx.y * 128, n0 = blockIdx.x * 128;
  const int wr = wid >> 1, wc = wid & 1;
  f32x4 acc[4][4] = {};
  const int srow  = t >> 2;
  const int sunit = (t & 3) ^ ((srow >> 1) & 3);
  const f16* ga0 = A  + (size_t)(r0 + srow) * 1024      + sunit * 8;
  const f16* ga1 = A  + (size_t)(r0 + 64 + srow) * 1024 + sunit * 8;
  const f16* gb0 = Bw + (size_t)(n0 + srow) * 1024      + sunit * 8;
  const f16* gb1 = Bw + (size_t)(n0 + 64 + srow) * 1024 + sunit * 8;
  int ra[4], rb[4];
  #pragma unroll
  for (int m = 0; m < 4; ++m) {
    int rr = wr * 64 + m * 16 + (lane & 15);
    ra[m] = rr * 32 + (((lane >> 4) ^ ((rr >> 1) & 3)) * 8);
    rr = wc * 64 + m * 16 + (lane & 15);
    rb[m] = rr * 32 + (((lane >> 4) ^ ((rr >> 1) & 3)) * 8);
  }
  const int ldst = wid * 512;
  #define STAGE_G(kt, bb) do { const int k0_ = (kt) * 32; \
      GLDS16(ga0 + k0_, As + (bb)*4096 + ldst); \
      GLDS16(ga1 + k0_, As + (bb)*4096 + 2048 + ldst); \
      GLDS16(gb0 + k0_, Bs + (bb)*4096 + ldst); \
      GLDS16(gb1 + k0_, Bs + (bb)*4096 + 2048 + ldst); } while(0)
  STAGE_G(0, 0);
  for (int kt = 0; kt < 32; ++kt) {
    const int cur = kt & 1;
    if (kt < 31) {
      STAGE_G(kt + 1, cur ^ 1);
      asm volatile("s_waitcnt vmcnt(4)" ::: "memory");
    } else {
      asm volatile("s_waitcnt vmcnt(0)" ::: "memory");
    }
    asm volatile("s_barrier" ::: "memory");
    f16x8 a[4], b[4];
    #pragma unroll
    for (int m = 0; m < 4; ++m) a[m] = *(const f16x8*)(As + cur*4096 + ra[m]);
    #pragma unroll
    for (int n = 0; n < 4; ++n) b[n] = *(const f16x8*)(Bs + cur*4096 + rb[n]);
    #pragma unroll
    for (int m = 0; m < 4; ++m)
      #pragma unroll
      for (int n = 0; n < 4; ++n)
        acc[m][n] = __builtin_amdgcn_mfma_f32_16x16x32_f16(a[m], b[n], acc[m][n], 0, 0, 0);
    asm volatile("s_waitcnt lgkmcnt(0)" ::: "memory");
    asm volatile("s_barrier" ::: "memory");
  }
  #undef STAGE_G
  #pragma unroll
  for (int n = 0; n < 4; ++n) {
    const int gn = n0 + wc * 64 + n * 16 + (lane & 15);
    const float bov = bo[gn];
    #pragma unroll
    for (int m = 0; m < 4; ++m) {
      const int rbase = r0 + wr * 64 + m * 16 + ((lane >> 4) << 2);
      #pragma unroll
      for (int r = 0; r < 4; ++r)
        out[(size_t)(rbase + r) * 1024 + gn] = acc[m][n][r] + bov;
    }
  }
}

// ---------------------------------------------------------------------------
extern "C" void kernel_launch(void* const* d_in, const int* in_sizes, int n_in,
                              void* d_out, int out_size, void* d_ws, size_t ws_size,
                              hipStream_t stream)
{
  const float* states = (const float*)d_in[0];
  const float* mask   = (const float*)d_in[1];
  const float* hs     = (const float*)d_in[2];
  const float* Wa     = (const float*)d_in[3];
  const float* Wv     = (const float*)d_in[4];
  const float* bv     = (const float*)d_in[5];
  const float* Wg     = (const float*)d_in[6];
  const float* bg     = (const float*)d_in[7];
  const float* Wo     = (const float*)d_in[8];
  const float* bo     = (const float*)d_in[9];
  float* out = (float*)d_out;

  // workspace layout (bytes): total 21,497,984 (~20.5 MB). og aliases st16:
  // st16 is consumed by k_gemm_v before k_attn writes og (stream-ordered).
  char* ws = (char*)d_ws;
  f16*   st16    = (f16*)(ws);                   //  8 MB  states fp16 [4096][1024]
  f16*   og      = (f16*)(ws);                   //  8 MB  gated O fp16 (alias)
  f16*   Wv16    = (f16*)(ws + 8388608);         //  2 MB
  f16*   Wo16    = (f16*)(ws + 10485760);        //  2 MB
  float* sbuf    = (float*)(ws + 12582912);      // 256 KB s [32][2048]
  float* gsig    = (float*)(ws + 12845056);      // 256 KB sigmoid(g) [4096][16]
  f16*   vt      = (f16*)(ws + 13107200);        //  8 MB  V^T [2048][2048]
  float* partial = (float*)(ws + 21495808);      //  2 KB  mask absmax partials (512)
  float* Lbuf    = (float*)(ws + 21497856);      // 128 B  logit upper bounds

  k_prep<<<3072, 256, 0, stream>>>(states, mask, Wa, Wv, Wg, Wo, bg,
                                   st16, Wv16, Wo16, sbuf, gsig, partial);
  k_lmax<<<32, 64, 0, stream>>>(sbuf, partial, hs, Lbuf);
  k_gemm_v<<<dim3(8, 32), 256, 0, stream>>>(st16, Wv16, bv, vt);
  k_attn<<<1024, 256, 0, stream>>>(mask, sbuf, gsig, hs, Lbuf, vt, og);
  k_gemm_out<<<dim3(8, 32), 256, 0, stream>>>(og, Wo16, bo, out);
}

// Round 5
// 166.533 us; speedup vs baseline: 1.3978x; 1.3978x over previous
//
#include <hip/hip_runtime.h>

// Problem constants: B=2, S=2048, D_MODEL=1024, H=16, DK=64.
// Workspace need: ~20.5 MB (og aliases st16; see kernel_launch).

#define LOG2E 1.44269504088896f

using f16   = _Float16;
using f16x4 = __attribute__((ext_vector_type(4))) _Float16;
using f16x8 = __attribute__((ext_vector_type(8))) _Float16;
using f32x4 = __attribute__((ext_vector_type(4))) float;

#define GLDS16(g, l) __builtin_amdgcn_global_load_lds((const __attribute__((address_space(1))) void*)(g), (__attribute__((address_space(3))) void*)(l), 16, 0, 0)
#define GLDS4(g, l)  __builtin_amdgcn_global_load_lds((const __attribute__((address_space(1))) void*)(g), (__attribute__((address_space(3))) void*)(l), 4, 0, 0)

// ---------------------------------------------------------------------------
// K1: blocks 0-1023:   s[b,h,k] = states·Wa  (wave per row) + states->fp16
//     blocks 1024-2047: gsig[b,q,h] = sigmoid(states·Wg + bg)
//     blocks 2048-3071: Wv/Wo -> fp16; cb<512: mask absmax partials
// ---------------------------------------------------------------------------
__global__ __launch_bounds__(256) void k_prep(
    const float* __restrict__ states, const float* __restrict__ mask,
    const float* __restrict__ Wa, const float* __restrict__ Wv,
    const float* __restrict__ Wg, const float* __restrict__ Wo,
    const float* __restrict__ bg,
    f16* __restrict__ st16, f16* __restrict__ Wv16, f16* __restrict__ Wo16,
    float* __restrict__ sbuf, float* __restrict__ gsig, float* __restrict__ partial)
{
  __shared__ float ws[16 * 1024];   // 64 KB
  const int bid = blockIdx.x;
  const int t   = threadIdx.x;
  if (bid < 2048) {
    const bool is_g = bid >= 1024;
    const float* W = is_g ? Wg : Wa;
    for (int i = t; i < 4096; i += 256)
      ((float4*)ws)[i] = ((const float4*)W)[i];
    __syncthreads();
    const int wid = t >> 6, lane = t & 63;
    const int row = (bid & 1023) * 4 + wid;           // 0..4095
    const float* sp = states + (size_t)row * 1024 + lane * 16;
    float x[16];
    #pragma unroll
    for (int j = 0; j < 4; ++j) {
      float4 v = ((const float4*)sp)[j];
      x[j*4+0]=v.x; x[j*4+1]=v.y; x[j*4+2]=v.z; x[j*4+3]=v.w;
    }
    if (!is_g) {
      f16x8 h0, h1;
      #pragma unroll
      for (int j = 0; j < 8; ++j) { h0[j] = (f16)x[j]; h1[j] = (f16)x[8+j]; }
      f16* dp = st16 + (size_t)row * 1024 + lane * 16;
      *(f16x8*)dp = h0; *(f16x8*)(dp + 8) = h1;
    }
    const int b = row >> 11, q = row & 2047;
    for (int h = 0; h < 16; ++h) {
      const float4* wr4 = (const float4*)(ws + h * 1024 + lane * 16);
      float acc = 0.f;
      #pragma unroll
      for (int j = 0; j < 4; ++j) {
        float4 wv4 = wr4[j];
        acc = fmaf(x[j*4+0], wv4.x, acc);
        acc = fmaf(x[j*4+1], wv4.y, acc);
        acc = fmaf(x[j*4+2], wv4.z, acc);
        acc = fmaf(x[j*4+3], wv4.w, acc);
      }
      #pragma unroll
      for (int off = 32; off; off >>= 1) acc += __shfl_xor(acc, off, 64);
      if (lane == 0) {
        if (!is_g) sbuf[(size_t)(b * 16 + h) * 2048 + q] = acc;
        else       gsig[(size_t)row * 16 + h] = 1.f / (1.f + __expf(-(acc + bg[h])));
      }
    }
  } else {
    const int cb = bid - 2048;                         // 0..1023
    { // weight convert: 2 M halves total, 2048 per block
      int idx = cb * 2048 + t * 8;
      const float* src; f16* dst;
      if (idx < 1048576) { src = Wv + idx;             dst = Wv16 + idx; }
      else               { src = Wo + (idx - 1048576); dst = Wo16 + (idx - 1048576); }
      float4 v0 = ((const float4*)src)[0];
      float4 v1 = ((const float4*)src)[1];
      f16x8 h;
      h[0]=(f16)v0.x; h[1]=(f16)v0.y; h[2]=(f16)v0.z; h[3]=(f16)v0.w;
      h[4]=(f16)v1.x; h[5]=(f16)v1.y; h[6]=(f16)v1.z; h[7]=(f16)v1.w;
      *(f16x8*)dst = h;
    }
    if (cb < 512) {
      // mask absmax partial: 512 chunks x 16384 floats = 8,388,608 = B*S*S
      const float4* mp = (const float4*)(mask + (size_t)cb * 16384);
      float mx = 0.f;
      for (int i = 0; i < 16; ++i) {
        float4 v = mp[t + i * 256];
        mx = fmaxf(mx, fmaxf(fmaxf(fabsf(v.x), fabsf(v.y)), fmaxf(fabsf(v.z), fabsf(v.w))));
      }
      #pragma unroll
      for (int off = 32; off; off >>= 1) mx = fmaxf(mx, __shfl_xor(mx, off, 64));
      if ((t & 63) == 0) ws[t >> 6] = mx;
      __syncthreads();
      if (t == 0) partial[cb] = fmaxf(fmaxf(ws[0], ws[1]), fmaxf(ws[2], ws[3]));
    }
  }
}

// ---------------------------------------------------------------------------
// K2: L[b,h] = max_k s[b,h,k] + head_scale[h] * max|mask_b|
// ---------------------------------------------------------------------------
__global__ __launch_bounds__(64) void k_lmax(
    const float* __restrict__ sbuf, const float* __restrict__ partial,
    const float* __restrict__ hs, float* __restrict__ Lbuf)
{
  const int bh = blockIdx.x, l = threadIdx.x;
  float mx = -1e30f;
  for (int i = l; i < 2048; i += 64) mx = fmaxf(mx, sbuf[(size_t)bh * 2048 + i]);
  float mm = 0.f;
  const int b = bh >> 4;
  for (int i = l; i < 256; i += 64) mm = fmaxf(mm, partial[b * 256 + i]);
  #pragma unroll
  for (int off = 32; off; off >>= 1) {
    mx = fmaxf(mx, __shfl_xor(mx, off, 64));
    mm = fmaxf(mm, __shfl_xor(mm, off, 64));
  }
  if (l == 0) Lbuf[bh] = mx + hs[bh & 15] * mm;
}

// ---------------------------------------------------------------------------
// K3: vt[(b*1024 + n)][k] = fp16( states[b,k,:]·Wv[n,:] + bv[n] ), V^T layout.
// 128(M)x64(N) tile, BK=32, 512 blocks (2/CU), dbuf + counted vmcnt,
// XCD swizzle n-fastest (B weight matrix 2MB L2-resident per XCD).
// ---------------------------------------------------------------------------
__global__ __launch_bounds__(256) void k_gemm_v(
    const f16* __restrict__ A, const f16* __restrict__ Bw,
    const float* __restrict__ bv, f16* __restrict__ vt)
{
  __shared__ f16 As[2 * 4096], Bs[2 * 2048];   // 16 KB + 8 KB
  const int p = blockIdx.x;
  const int l = (p & 7) * 64 + (p >> 3);       // bijective: 512 = 8*64
  const int r0 = (l >> 4) * 128, n0 = (l & 15) * 64;
  const int t = threadIdx.x, wid = t >> 6, lane = t & 63;
  const int lane15 = lane & 15, lg = lane >> 4;
  const int wr = wid >> 1, wc = wid & 1;
  f32x4 acc[4][2] = {};
  const int sswz = ((t & 3) ^ ((t >> 3) & 3)) * 8;
  const f16* ga0 = A  + (size_t)(r0 + (t >> 2)) * 1024       + sswz;
  const f16* ga1 = A  + (size_t)(r0 + 64 + (t >> 2)) * 1024  + sswz;
  const f16* gb0 = Bw + (size_t)(n0 + (t >> 2)) * 1024       + sswz;
  int ra[4], rb[2];
  #pragma unroll
  for (int m = 0; m < 4; ++m) { int r_ = wr*64 + m*16 + lane15; ra[m] = r_*32 + ((lg ^ ((r_>>1)&3)) * 8); }
  #pragma unroll
  for (int n = 0; n < 2; ++n) { int r_ = wc*32 + n*16 + lane15; rb[n] = r_*32 + ((lg ^ ((r_>>1)&3)) * 8); }

  #define STAGE_G(kt, bb) do { const int k0_ = (kt) * 32; \
      GLDS16(ga0 + k0_, As + (bb)*4096 + wid*512); \
      GLDS16(ga1 + k0_, As + (bb)*4096 + 2048 + wid*512); \
      GLDS16(gb0 + k0_, Bs + (bb)*2048 + wid*512); } while(0)
  STAGE_G(0, 0);
  for (int kt = 0; kt < 32; ++kt) {
    const int cur = kt & 1;
    if (kt < 31) {
      STAGE_G(kt + 1, cur ^ 1);
      asm volatile("s_waitcnt vmcnt(3)" ::: "memory");
    } else {
      asm volatile("s_waitcnt vmcnt(0)" ::: "memory");
    }
    __builtin_amdgcn_s_barrier();
    f16x8 a[4], bf[2];
    #pragma unroll
    for (int m = 0; m < 4; ++m) a[m] = *(const f16x8*)(As + cur*4096 + ra[m]);
    #pragma unroll
    for (int n = 0; n < 2; ++n) bf[n] = *(const f16x8*)(Bs + cur*2048 + rb[n]);
    #pragma unroll
    for (int m = 0; m < 4; ++m)
      #pragma unroll
      for (int n = 0; n < 2; ++n)
        acc[m][n] = __builtin_amdgcn_mfma_f32_16x16x32_f16(a[m], bf[n], acc[m][n], 0, 0, 0);
    asm volatile("s_waitcnt lgkmcnt(0)" ::: "memory");
    __builtin_amdgcn_s_barrier();
  }
  #undef STAGE_G
  const int b_ = r0 >> 11;
  #pragma unroll
  for (int n = 0; n < 2; ++n) {
    const int gn = n0 + wc * 32 + n * 16 + lane15;
    const float bvv = bv[gn];
    #pragma unroll
    for (int m = 0; m < 4; ++m) {
      const int kb = (r0 & 2047) + wr * 64 + m * 16 + lg * 4;
      f16x4 hv;
      #pragma unroll
      for (int r = 0; r < 4; ++r) hv[r] = (f16)(acc[m][n][r] + bvv);
      *(f16x4*)(vt + (size_t)(b_ * 1024 + gn) * 2048 + kb) = hv;
    }
  }
}

// ---------------------------------------------------------------------------
// K4: fused attention v4 (R2 base, de-risked). Block=(h, qt=64, b), 4 waves.
// Fragment-direct softmax: wave owns q rows wid*16..+16; lane computes exp
// for exactly its MFMA A-fragment elems (q=wid*16+lane15, k=kk*32+lg*8+j)
// -> NO P LDS round-trip, acc[4] only (16 VGPRs). mask+V+s double-buffered
// via global_load_lds w/ pre-swizzled sources, counted vmcnt. 2 barriers/it.
// XCD swizzle: each XCD = one b, 8 qt x 16 h -> mask tile L2-reused 16x.
// ---------------------------------------------------------------------------
__global__ __launch_bounds__(256, 3) void k_attn(
    const float* __restrict__ mask, const float* __restrict__ sbuf,
    const float* __restrict__ gsig, const float* __restrict__ hs,
    const float* __restrict__ Lbuf, const f16* __restrict__ vt,
    f16* __restrict__ og)
{
  __shared__ __align__(16) float mk[2 * 4096];   // 32 KB mask dbuf [64q][16 slots x4f] swz
  __shared__ __align__(16) f16   vs[2 * 4096];   // 16 KB V dbuf [64d][8 slots x8h] swz
  __shared__ __align__(16) float stb[2 * 64];    // 512 B s dbuf

  const int p = blockIdx.x;                      // 0..1023
  const int l = (p & 7) * 128 + (p >> 3);        // bijective chunked XCD swizzle
  const int b = l >> 9, rr = l & 511;
  const int qt = rr >> 4, h = rr & 15;

  const int t = threadIdx.x, wid = t >> 6, lane = t & 63;
  const int lane15 = lane & 15, lg = lane >> 4;
  const float L   = Lbuf[b * 16 + h];
  const float c2  = hs[h] * LOG2E;
  const float nLc = -L * LOG2E;

  const float* mbase = mask + (size_t)b * 4194304 + (size_t)(qt * 64) * 2048;
  const f16*   vtb   = vt + (size_t)(b * 1024 + h * 64) * 2048;
  const float* sb    = sbuf + (size_t)(b * 16 + h) * 2048;

  // staging sources (pre-swizzled, k0-invariant)
  const int mswz = ((t & 15) ^ ((t >> 4) & 7)) * 4;
  const float* msrc0 = mbase + (size_t)(     (t >> 4)) * 2048 + mswz;
  const float* msrc1 = mbase + (size_t)(16 + (t >> 4)) * 2048 + mswz;
  const float* msrc2 = mbase + (size_t)(32 + (t >> 4)) * 2048 + mswz;
  const float* msrc3 = mbase + (size_t)(48 + (t >> 4)) * 2048 + mswz;
  const int vswz = ((t & 7) ^ ((t >> 3) & 7)) * 8;
  const f16* vsrc0 = vtb + (size_t)(     (t >> 3)) * 2048 + vswz;
  const f16* vsrc1 = vtb + (size_t)(32 + (t >> 3)) * 2048 + vswz;
  const float* ssrc = sb + lane;                 // wid==0 only

  // read offsets (fragment layout), element units
  const int q16 = wid * 16 + lane15;             // this thread's q row (0..63)
  int moff[2][2], voff[2][4];
  #pragma unroll
  for (int kk = 0; kk < 2; ++kk) {
    const int sl = kk * 8 + lg * 2;
    moff[kk][0] = q16 * 64 + ((sl    ) ^ (q16 & 7)) * 4;
    moff[kk][1] = q16 * 64 + ((sl + 1) ^ (q16 & 7)) * 4;
    #pragma unroll
    for (int n = 0; n < 4; ++n)
      voff[kk][n] = (n * 16 + lane15) * 64 + (((kk * 4 + lg) ^ (lane15 & 7)) * 8);
  }

  f32x4 acc[4] = {};
  float den = 0.f;

  #define STAGE(kt, bb) do { const int k0_ = (kt) * 64; \
      GLDS16(msrc0 + k0_, mk + (bb)*4096 +        wid*256); \
      GLDS16(msrc1 + k0_, mk + (bb)*4096 + 1024 + wid*256); \
      GLDS16(msrc2 + k0_, mk + (bb)*4096 + 2048 + wid*256); \
      GLDS16(msrc3 + k0_, mk + (bb)*4096 + 3072 + wid*256); \
      GLDS16(vsrc0 + k0_, vs + (bb)*4096 +        wid*512); \
      GLDS16(vsrc1 + k0_, vs + (bb)*4096 + 2048 + wid*512); \
      if (wid == 0) GLDS4(ssrc + k0_, stb + (bb)*64); } while(0)

  STAGE(0, 0);
  for (int kt = 0; kt < 32; ++kt) {
    const int cur = kt & 1;
    if (kt < 31) {
      STAGE(kt + 1, cur ^ 1);
      if (wid == 0) asm volatile("s_waitcnt vmcnt(7)" ::: "memory");
      else          asm volatile("s_waitcnt vmcnt(6)" ::: "memory");
    } else {
      asm volatile("s_waitcnt vmcnt(0)" ::: "memory");
    }
    __builtin_amdgcn_s_barrier();

    const float* mkc = mk + cur * 4096;
    const f16*   vsc = vs + cur * 4096;
    const float* stc = stb + cur * 64;

    #pragma unroll
    for (int kk = 0; kk < 2; ++kk) {
      f32x4 s4a = *(const f32x4*)(stc + kk * 32 + lg * 8);
      f32x4 s4b = *(const f32x4*)(stc + kk * 32 + lg * 8 + 4);
      f32x4 ma  = *(const f32x4*)(mkc + moff[kk][0]);
      f32x4 mb  = *(const f32x4*)(mkc + moff[kk][1]);
      f16x8 vf0 = *(const f16x8*)(vsc + voff[kk][0]);
      f16x8 vf1 = *(const f16x8*)(vsc + voff[kk][1]);
      f16x8 vf2 = *(const f16x8*)(vsc + voff[kk][2]);
      f16x8 vf3 = *(const f16x8*)(vsc + voff[kk][3]);
      f16x8 af;
      float w0 = __builtin_amdgcn_exp2f(fmaf(c2, ma[0], fmaf(s4a[0], LOG2E, nLc)));
      float w1 = __builtin_amdgcn_exp2f(fmaf(c2, ma[1], fmaf(s4a[1], LOG2E, nLc)));
      float w2 = __builtin_amdgcn_exp2f(fmaf(c2, ma[2], fmaf(s4a[2], LOG2E, nLc)));
      float w3 = __builtin_amdgcn_exp2f(fmaf(c2, ma[3], fmaf(s4a[3], LOG2E, nLc)));
      float w4 = __builtin_amdgcn_exp2f(fmaf(c2, mb[0], fmaf(s4b[0], LOG2E, nLc)));
      float w5 = __builtin_amdgcn_exp2f(fmaf(c2, mb[1], fmaf(s4b[1], LOG2E, nLc)));
      float w6 = __builtin_amdgcn_exp2f(fmaf(c2, mb[2], fmaf(s4b[2], LOG2E, nLc)));
      float w7 = __builtin_amdgcn_exp2f(fmaf(c2, mb[3], fmaf(s4b[3], LOG2E, nLc)));
      af[0]=(f16)w0; af[1]=(f16)w1; af[2]=(f16)w2; af[3]=(f16)w3;
      af[4]=(f16)w4; af[5]=(f16)w5; af[6]=(f16)w6; af[7]=(f16)w7;
      den += ((w0 + w1) + (w2 + w3)) + ((w4 + w5) + (w6 + w7));
      acc[0] = __builtin_amdgcn_mfma_f32_16x16x32_f16(af, vf0, acc[0], 0, 0, 0);
      acc[1] = __builtin_amdgcn_mfma_f32_16x16x32_f16(af, vf1, acc[1], 0, 0, 0);
      acc[2] = __builtin_amdgcn_mfma_f32_16x16x32_f16(af, vf2, acc[2], 0, 0, 0);
      acc[3] = __builtin_amdgcn_mfma_f32_16x16x32_f16(af, vf3, acc[3], 0, 0, 0);
    }
    asm volatile("s_waitcnt lgkmcnt(0)" ::: "memory");
    __builtin_amdgcn_s_barrier();
  }
  #undef STAGE

  // den: sum over lg groups -> every lane holds full den for q=wid*16+lane15
  den += __shfl_xor(den, 16, 64);
  den += __shfl_xor(den, 32, 64);

  // epilogue: C row = wid*16 + lg*4 + r, col = n*16 + lane15
  #pragma unroll
  for (int r = 0; r < 4; ++r) {
    const int ql = lg * 4 + r;
    const int q = qt * 64 + wid * 16 + ql;
    const float dq = __shfl(den, ql, 64);        // lane ql has lane15==ql
    const float sc = gsig[(size_t)(b * 2048 + q) * 16 + h] / dq;
    #pragma unroll
    for (int n = 0; n < 4; ++n)
      og[(size_t)(b * 2048 + q) * 1024 + h * 64 + n * 16 + lane15] = (f16)(acc[n][r] * sc);
  }
}

// ---------------------------------------------------------------------------
// K5: out[r][n] = og[r,:]·Wo[n,:] + bo[n]  (f32 out). Same 128x64 structure.
// ---------------------------------------------------------------------------
__global__ __launch_bounds__(256) void k_gemm_out(
    const f16* __restrict__ A, const f16* __restrict__ Bw,
    const float* __restrict__ bo, float* __restrict__ out)
{
  __shared__ f16 As[2 * 4096], Bs[2 * 2048];
  const int p = blockIdx.x;
  const int l = (p & 7) * 64 + (p >> 3);
  const int r0 = (l >> 4) * 128, n0 = (l & 15) * 64;
  const int t = threadIdx.x, wid = t >> 6, lane = t & 63;
  const int lane15 = lane & 15, lg = lane >> 4;
  const int wr = wid >> 1, wc = wid & 1;
  f32x4 acc[4][2] = {};
  const int sswz = ((t & 3) ^ ((t >> 3) & 3)) * 8;
  const f16* ga0 = A  + (size_t)(r0 + (t >> 2)) * 1024       + sswz;
  const f16* ga1 = A  + (size_t)(r0 + 64 + (t >> 2)) * 1024  + sswz;
  const f16* gb0 = Bw + (size_t)(n0 + (t >> 2)) * 1024       + sswz;
  int ra[4], rb[2];
  #pragma unroll
  for (int m = 0; m < 4; ++m) { int r_ = wr*64 + m*16 + lane15; ra[m] = r_*32 + ((lg ^ ((r_>>1)&3)) * 8); }
  #pragma unroll
  for (int n = 0; n < 2; ++n) { int r_ = wc*32 + n*16 + lane15; rb[n] = r_*32 + ((lg ^ ((r_>>1)&3)) * 8); }

  #define STAGE_G(kt, bb) do { const int k0_ = (kt) * 32; \
      GLDS16(ga0 + k0_, As + (bb)*4096 + wid*512); \
      GLDS16(ga1 + k0_, As + (bb)*4096 + 2048 + wid*512); \
      GLDS16(gb0 + k0_, Bs + (bb)*2048 + wid*512); } while(0)
  STAGE_G(0, 0);
  for (int kt = 0; kt < 32; ++kt) {
    const int cur = kt & 1;
    if (kt < 31) {
      STAGE_G(kt + 1, cur ^ 1);
      asm volatile("s_waitcnt vmcnt(3)" ::: "memory");
    } else {
      asm volatile("s_waitcnt vmcnt(0)" ::: "memory");
    }
    __builtin_amdgcn_s_barrier();
    f16x8 a[4], bf[2];
    #pragma unroll
    for (int m = 0; m < 4; ++m) a[m] = *(const f16x8*)(As + cur*4096 + ra[m]);
    #pragma unroll
    for (int n = 0; n < 2; ++n) bf[n] = *(const f16x8*)(Bs + cur*2048 + rb[n]);
    #pragma unroll
    for (int m = 0; m < 4; ++m)
      #pragma unroll
      for (int n = 0; n < 2; ++n)
        acc[m][n] = __builtin_amdgcn_mfma_f32_16x16x32_f16(a[m], bf[n], acc[m][n], 0, 0, 0);
    asm volatile("s_waitcnt lgkmcnt(0)" ::: "memory");
    __builtin_amdgcn_s_barrier();
  }
  #undef STAGE_G
  #pragma unroll
  for (int n = 0; n < 2; ++n) {
    const int gn = n0 + wc * 32 + n * 16 + lane15;
    const float bov = bo[gn];
    #pragma unroll
    for (int m = 0; m < 4; ++m) {
      const int rbase = r0 + wr * 64 + m * 16 + lg * 4;
      #pragma unroll
      for (int r = 0; r < 4; ++r)
        out[(size_t)(rbase + r) * 1024 + gn] = acc[m][n][r] + bov;
    }
  }
}

// ---------------------------------------------------------------------------
extern "C" void kernel_launch(void* const* d_in, const int* in_sizes, int n_in,
                              void* d_out, int out_size, void* d_ws, size_t ws_size,
                              hipStream_t stream)
{
  const float* states = (const float*)d_in[0];
  const float* mask   = (const float*)d_in[1];
  const float* hs     = (const float*)d_in[2];
  const float* Wa     = (const float*)d_in[3];
  const float* Wv     = (const float*)d_in[4];
  const float* bv     = (const float*)d_in[5];
  const float* Wg     = (const float*)d_in[6];
  const float* bg     = (const float*)d_in[7];
  const float* Wo     = (const float*)d_in[8];
  const float* bo     = (const float*)d_in[9];
  float* out = (float*)d_out;

  // workspace layout (bytes): total 21,497,984 (~20.5 MB). og aliases st16:
  // st16 is consumed by k_gemm_v before k_attn writes og (stream-ordered).
  char* ws = (char*)d_ws;
  f16*   st16    = (f16*)(ws);                   //  8 MB  states fp16 [4096][1024]
  f16*   og      = (f16*)(ws);                   //  8 MB  gated O fp16 (alias)
  f16*   Wv16    = (f16*)(ws + 8388608);         //  2 MB
  f16*   Wo16    = (f16*)(ws + 10485760);        //  2 MB
  float* sbuf    = (float*)(ws + 12582912);      // 256 KB s [32][2048]
  float* gsig    = (float*)(ws + 12845056);      // 256 KB sigmoid(g) [4096][16]
  f16*   vt      = (f16*)(ws + 13107200);        //  8 MB  V^T [2048][2048]
  float* partial = (float*)(ws + 21495808);      //  2 KB  mask absmax partials (512)
  float* Lbuf    = (float*)(ws + 21497856);      // 128 B  logit upper bounds

  k_prep<<<3072, 256, 0, stream>>>(states, mask, Wa, Wv, Wg, Wo, bg,
                                   st16, Wv16, Wo16, sbuf, gsig, partial);
  k_lmax<<<32, 64, 0, stream>>>(sbuf, partial, hs, Lbuf);
  k_gemm_v<<<512, 256, 0, stream>>>(st16, Wv16, bv, vt);
  k_attn<<<1024, 256, 0, stream>>>(mask, sbuf, gsig, hs, Lbuf, vt, og);
  k_gemm_out<<<512, 256, 0, stream>>>(og, Wo16, bo, out);
}